// Round 1
// baseline (3205.278 us; speedup 1.0000x reference)
//
#include <hip/hip_runtime.h>
#include <hip/hip_bf16.h>

// ---------------- problem constants ----------------
#define NN 30000
#define NE 480000
#define CIN 64
#define KK 25
#define KD 1600          // 25*64 spline-K dimension
#define KT 1664          // + 64 root-append columns
#define KTILES 52        // 1664 / 32
#define KPA 1672         // padded A-tile row stride (elements); 836 words % 32 == 4 -> conflict-optimal
#define NT 8             // nodes per fused block
#define NB_FUSED (NN/NT) // 3750
#define REG_OFF  (30000*101)
#define OBJ_OFF  (30000*105)

typedef short bf16x8 __attribute__((ext_vector_type(8)));
typedef float f32x4  __attribute__((ext_vector_type(4)));

__device__ __forceinline__ ushort f2bf(float x) {
    union { float f; unsigned u; } v; v.f = x;
    unsigned r = v.u + 0x7FFFu + ((v.u >> 16) & 1u);   // RNE
    return (ushort)(r >> 16);
}

// ---------------- graph preprocessing ----------------
__global__ void k_count(const int* __restrict__ dst, int* __restrict__ deg) {
    int e = blockIdx.x * 256 + threadIdx.x;
    if (e < NE) atomicAdd(&deg[dst[e]], 1);
}

__global__ void k_scan(const int* __restrict__ deg, int* __restrict__ rp,
                       int* __restrict__ cur, float* __restrict__ invd) {
    __shared__ int s[1024];
    int t = threadIdx.x;
    const int CH = 30;                       // 1024*30 >= 30000
    int base = t * CH, loc = 0;
    for (int i = 0; i < CH; ++i) { int n = base + i; if (n < NN) loc += deg[n]; }
    s[t] = loc; __syncthreads();
    for (int o = 1; o < 1024; o <<= 1) {
        int v = (t >= o) ? s[t - o] : 0;
        __syncthreads(); s[t] += v; __syncthreads();
    }
    int run = s[t] - loc;                    // exclusive prefix for this chunk
    for (int i = 0; i < CH; ++i) {
        int n = base + i;
        if (n < NN) {
            int dg = deg[n];
            rp[n] = run; cur[n] = run;
            invd[n] = 1.f / (float)(dg > 0 ? dg : 1);
            run += dg;
        }
    }
    if (t == 0) rp[NN] = NE;
}

// compute spline basis per edge and scatter metadata into dst-sorted order
__global__ void k_scatter(const float* __restrict__ ea, const int* __restrict__ src,
                          const int* __restrict__ dst, int* __restrict__ cur,
                          float4* __restrict__ mB, int4* __restrict__ mI) {
    int e = blockIdx.x * 256 + threadIdx.x;
    if (e >= NE) return;
    float p0 = ea[e*3+0], p1 = ea[e*3+1];
    float v0 = p0*4.f, v1 = p1*4.f;
    float b0 = fminf(fmaxf(floorf(v0),0.f),4.f);
    float b1 = fminf(fmaxf(floorf(v1),0.f),4.f);
    float f0 = v0-b0, f1 = v1-b1;
    int i0 = (int)b0, i1 = (int)b1;
    float Bv[4]; int kv[4];
    #pragma unroll
    for (int j = 0; j < 4; ++j) {
        int bit0 = j >> 1, bit1 = j & 1;
        int q0 = i0 + bit0; if (q0 > 4) q0 = 4;
        int q1 = i1 + bit1; if (q1 > 4) q1 = 4;
        float w0 = bit0 ? f0 : 1.f - f0;
        float w1 = bit1 ? f1 : 1.f - f1;
        Bv[j] = w0 * w1; kv[j] = q0*5 + q1;
    }
    unsigned kp = (unsigned)kv[0] | ((unsigned)kv[1]<<8) | ((unsigned)kv[2]<<16) | ((unsigned)kv[3]<<24);
    int dn = dst[e];
    int pos = atomicAdd(&cur[dn], 1);
    mB[pos] = make_float4(Bv[0],Bv[1],Bv[2],Bv[3]);
    mI[pos] = make_int4((int)kp, src[e], dn, 0);
}

// transpose+bf16 all 6 weight sets: Wt[d][kc] = W[kc][d] (kc<1600), = root[kc-1600][d]
__global__ void k_prepw(const float* W1,const float* R1,const float* W2,const float* R2,
                        const float* W3,const float* R3,const float* Wr,const float* Rr,
                        const float* Wc,const float* Rc,const float* Wo,const float* Ro,
                        ushort* T1, ushort* T2, ushort* T3, ushort* Tr, ushort* Tc, ushort* To) {
    int b = blockIdx.x;
    const float* W; const float* R; ushort* T; int od; int d;
    if      (b < 64)  { W=W1; R=R1; T=T1; od=64;  d=b;     }
    else if (b < 128) { W=W2; R=R2; T=T2; od=64;  d=b-64;  }
    else if (b < 192) { W=W3; R=R3; T=T3; od=64;  d=b-128; }
    else if (b < 208) { W=Wr; R=Rr; T=Tr; od=4;   d=b-192; }
    else if (b < 320) { W=Wc; R=Rc; T=Tc; od=101; d=b-208; }
    else              { W=Wo; R=Ro; T=To; od=1;   d=b-320; }
    for (int kc = threadIdx.x; kc < KT; kc += 256) {
        float v = 0.f;
        if (d < od) v = (kc < KD) ? W[(long)kc*od + d] : R[(long)(kc-KD)*od + d];
        T[(long)d*KT + kc] = f2bf(v);
    }
}

// ---------------- fused spline-conv building blocks ----------------
// aggregate 8 nodes into LDS f32, then convert in place to bf16 A-tile
// A[i][kc<1600] = acc[i][kc] * inv_deg, A[i][1600+c] = f[n0+i][c] (root append)
__device__ __forceinline__ void build_tile(int n0, const int* __restrict__ rp,
        const float4* __restrict__ mB, const int4* __restrict__ mI,
        const float* __restrict__ f, const float* __restrict__ invd,
        float* accf, ushort* accbh) {
    const int tid = threadIdx.x;
    for (int q = tid; q < NT*KD/4; q += 256) ((float4*)accf)[q] = make_float4(0,0,0,0);
    __syncthreads();
    const int j = tid >> 6, c = tid & 63;     // wave = corner, lane = channel
    int beg = rp[n0], end = rp[n0 + NT];
    #pragma unroll 2
    for (int ei = beg; ei < end; ++ei) {
        float4 b4 = mB[ei];
        int4  i4 = mI[ei];
        float B = (j==0) ? b4.x : (j==1) ? b4.y : (j==2) ? b4.z : b4.w;
        int k = (i4.x >> (8*j)) & 0xFF;
        float xv = f[(long)i4.y * CIN + c];
        int row = i4.z - n0;
        atomicAdd(accf + row*KD + k*CIN + c, B * xv);
    }
    __syncthreads();
    // stage to registers (in-place f32 -> bf16 rewrite)
    float4 st[13];
    #pragma unroll
    for (int u = 0; u < 13; ++u) {
        int q = tid + (u << 8);
        if (q < NT*KD/4) st[u] = ((const float4*)accf)[q];
    }
    float fa0 = f[(long)(n0 + (tid >> 6))*CIN + (tid & 63)];
    int t2 = tid + 256;
    float fa1 = f[(long)(n0 + (t2 >> 6))*CIN + (t2 & 63)];
    __syncthreads();
    #pragma unroll
    for (int u = 0; u < 13; ++u) {
        int q = tid + (u << 8);
        if (q < NT*KD/4) {
            int row = q / 400;            // 400 float4 per row
            int c4  = (q % 400) * 4;
            float s = invd[n0 + row];
            ushort4 o;
            o.x = f2bf(st[u].x * s); o.y = f2bf(st[u].y * s);
            o.z = f2bf(st[u].z * s); o.w = f2bf(st[u].w * s);
            *(ushort4*)(accbh + row*KPA + c4) = o;
        }
    }
    accbh[(tid >> 6)*KPA + KD + (tid & 63)] = f2bf(fa0);
    accbh[(t2  >> 6)*KPA + KD + (t2  & 63)] = f2bf(fa1);
    __syncthreads();
}

// one 16-col N-tile GEMM sweep: rows 0-7 valid (8-15 duplicate rows 0-7)
__device__ __forceinline__ f32x4 sweep(const ushort* accbh, const ushort* __restrict__ wt) {
    const int l = threadIdx.x & 63;
    const ushort* ap = accbh + (l & 7)*KPA + ((l >> 4) << 3);
    const ushort* bp = wt + (long)(l & 15)*KT + ((l >> 4) << 3);
    f32x4 d = {0.f,0.f,0.f,0.f};
    #pragma unroll
    for (int kt = 0; kt < KTILES; ++kt) {
        bf16x8 a = *(const bf16x8*)(ap + kt*32);
        bf16x8 b = *(const bf16x8*)(bp + kt*32);
        d = __builtin_amdgcn_mfma_f32_16x16x32_bf16(a, b, d, 0, 0, 0);
    }
    return d;
}

template<bool STATS, bool BIAS>
__device__ __forceinline__ void epilogue(f32x4 d, int n0, int colbase, int od, int ostride,
        const float* __restrict__ bias, float* __restrict__ out, float* __restrict__ stats) {
    const int l = threadIdx.x & 63;
    if (l >= 32) return;                      // lanes 32-63 hold duplicate rows
    int col = colbase + (l & 15);
    int rb = (l >> 4) << 2;                   // 0 or 4
    float bv = (BIAS && col < od) ? bias[col] : 0.f;
    float s1 = 0.f, s2 = 0.f;
    #pragma unroll
    for (int r = 0; r < 4; ++r) {
        float v = d[r] + bv;
        if (col < od) out[(long)(n0 + rb + r)*ostride + col] = v;
        s1 += v; s2 += v * v;
    }
    if (STATS) {
        s1 += __shfl_down(s1, 16);
        s2 += __shfl_down(s2, 16);
        if (l < 16) { atomicAdd(&stats[col], s1); atomicAdd(&stats[64 + col], s2); }
    }
}

// ---------------- fused conv kernels ----------------
__global__ __launch_bounds__(256,2) void k_conv1(const int* rp, const float4* mB, const int4* mI,
        const float* x, const float* invd, const ushort* T1, float* y1, float* st1) {
    __shared__ float accf[NT*KD];
    ushort* accbh = (ushort*)accf;
    int n0 = blockIdx.x * NT;
    build_tile(n0, rp, mB, mI, x, invd, accf, accbh);
    int w = threadIdx.x >> 6;
    f32x4 d = sweep(accbh, T1 + (long)(w << 4)*KT);
    epilogue<true,false>(d, n0, w << 4, 64, 64, nullptr, y1, st1);
}

__global__ __launch_bounds__(256,2) void k_conv23(const int* rp, const float4* mB, const int4* mI,
        const float* x1, const float* invd, const ushort* T2, const ushort* T3,
        float* y2, float* y3, float* st2, float* st3) {
    __shared__ float accf[NT*KD];
    ushort* accbh = (ushort*)accf;
    int n0 = blockIdx.x * NT;
    build_tile(n0, rp, mB, mI, x1, invd, accf, accbh);
    int w = threadIdx.x >> 6;
    f32x4 d2 = sweep(accbh, T2 + (long)(w << 4)*KT);
    epilogue<true,false>(d2, n0, w << 4, 64, 64, nullptr, y2, st2);
    f32x4 d3 = sweep(accbh, T3 + (long)(w << 4)*KT);
    epilogue<true,false>(d3, n0, w << 4, 64, 64, nullptr, y3, st3);
}

__global__ __launch_bounds__(256,2) void k_regr(const int* rp, const float4* mB, const int4* mI,
        const float* x2, const float* invd, const ushort* Tr, const float* bias, float* outr) {
    __shared__ float accf[NT*KD];
    ushort* accbh = (ushort*)accf;
    int n0 = blockIdx.x * NT;
    build_tile(n0, rp, mB, mI, x2, invd, accf, accbh);
    if (threadIdx.x < 64) {
        f32x4 d = sweep(accbh, Tr);
        epilogue<false,true>(d, n0, 0, 4, 4, bias, outr, nullptr);
    }
}

__global__ __launch_bounds__(256,2) void k_clsobj(const int* rp, const float4* mB, const int4* mI,
        const float* x3, const float* invd, const ushort* Tc, const ushort* To,
        const float* bc, const float* bo, float* outc, float* outo) {
    __shared__ float accf[NT*KD];
    ushort* accbh = (ushort*)accf;
    int n0 = blockIdx.x * NT;
    build_tile(n0, rp, mB, mI, x3, invd, accf, accbh);
    int w = threadIdx.x >> 6;
    f32x4 dc = sweep(accbh, Tc + (long)(w << 4)*KT);
    epilogue<false,true>(dc, n0, w << 4, 101, 101, bc, outc, nullptr);
    if (w < 3) {
        f32x4 dc2 = sweep(accbh, Tc + (long)((w + 4) << 4)*KT);
        epilogue<false,true>(dc2, n0, (w + 4) << 4, 101, 101, bc, outc, nullptr);
    } else {
        f32x4 dob = sweep(accbh, To);
        epilogue<false,true>(dob, n0, 0, 1, 1, bo, outo, nullptr);
    }
}

// ---------------- BN + ReLU ----------------
__global__ void k_bnrelu(const float* __restrict__ y, const float* __restrict__ st,
                         const float* __restrict__ g, const float* __restrict__ bb,
                         float* __restrict__ xo) {
    int idx = blockIdx.x * 256 + threadIdx.x;
    if (idx >= NN*CIN) return;
    int d = idx & 63;
    const float inv_n = 1.f / (float)NN;
    float m = st[d] * inv_n;
    float var = st[64 + d] * inv_n - m * m;
    float v = (y[idx] - m) * rsqrtf(var + 1e-5f) * g[d] + bb[d];
    xo[idx] = fmaxf(v, 0.f);
}

// ---------------- host launch ----------------
extern "C" void kernel_launch(void* const* d_in, const int* in_sizes, int n_in,
                              void* d_out, int out_size, void* d_ws, size_t ws_size,
                              hipStream_t stream) {
    const float* x    = (const float*)d_in[0];
    const float* ea   = (const float*)d_in[1];
    const int*   src  = (const int*)d_in[2];
    const int*   dst  = (const int*)d_in[3];
    const float* W1   = (const float*)d_in[4];
    const float* R1   = (const float*)d_in[5];
    const float* g1   = (const float*)d_in[6];
    const float* be1  = (const float*)d_in[7];
    const float* W2   = (const float*)d_in[8];
    const float* R2   = (const float*)d_in[9];
    const float* g2   = (const float*)d_in[10];
    const float* be2  = (const float*)d_in[11];
    const float* W3   = (const float*)d_in[12];
    const float* R3   = (const float*)d_in[13];
    const float* g3   = (const float*)d_in[14];
    const float* be3  = (const float*)d_in[15];
    const float* Wr   = (const float*)d_in[16];
    const float* Rr   = (const float*)d_in[17];
    const float* br   = (const float*)d_in[18];
    const float* Wc   = (const float*)d_in[19];
    const float* Rc   = (const float*)d_in[20];
    const float* bc   = (const float*)d_in[21];
    const float* Wo   = (const float*)d_in[22];
    const float* Ro   = (const float*)d_in[23];
    const float* bo   = (const float*)d_in[24];
    float* out = (float*)d_out;

    char* p = (char*)d_ws;
    auto alloc = [&](size_t bytes) { char* r = p; p += (bytes + 255) & ~(size_t)255; return r; };
    float4* mB   = (float4*)alloc((size_t)NE * 16);
    int4*   mI   = (int4*)  alloc((size_t)NE * 16);
    int*    deg  = (int*)   alloc((size_t)NN * 4);
    int*    rp   = (int*)   alloc((size_t)(NN + 1) * 4);
    int*    cur  = (int*)   alloc((size_t)NN * 4);
    float*  invd = (float*) alloc((size_t)NN * 4);
    ushort* T1   = (ushort*)alloc((size_t)64  * KT * 2);
    ushort* T2   = (ushort*)alloc((size_t)64  * KT * 2);
    ushort* T3   = (ushort*)alloc((size_t)64  * KT * 2);
    ushort* Tr   = (ushort*)alloc((size_t)16  * KT * 2);
    ushort* Tc   = (ushort*)alloc((size_t)112 * KT * 2);
    ushort* To   = (ushort*)alloc((size_t)16  * KT * 2);
    float*  y1   = (float*) alloc((size_t)NN * CIN * 4);
    float*  y2   = (float*) alloc((size_t)NN * CIN * 4);
    float*  y3   = (float*) alloc((size_t)NN * CIN * 4);
    float*  x1   = (float*) alloc((size_t)NN * CIN * 4);
    float*  x2   = (float*) alloc((size_t)NN * CIN * 4);
    float*  x3   = (float*) alloc((size_t)NN * CIN * 4);
    float*  stats= (float*) alloc(3 * 128 * 4);
    float* st1 = stats, *st2 = stats + 128, *st3 = stats + 256;

    hipMemsetAsync(deg, 0, (size_t)NN * 4, stream);
    hipMemsetAsync(stats, 0, 3 * 128 * 4, stream);

    k_count  <<<1875, 256, 0, stream>>>(dst, deg);
    k_scan   <<<1, 1024, 0, stream>>>(deg, rp, cur, invd);
    k_scatter<<<1875, 256, 0, stream>>>(ea, src, dst, cur, mB, mI);
    k_prepw  <<<336, 256, 0, stream>>>(W1,R1,W2,R2,W3,R3,Wr,Rr,Wc,Rc,Wo,Ro,T1,T2,T3,Tr,Tc,To);

    k_conv1  <<<NB_FUSED, 256, 0, stream>>>(rp, mB, mI, x, invd, T1, y1, st1);
    k_bnrelu <<<7500, 256, 0, stream>>>(y1, st1, g1, be1, x1);
    k_conv23 <<<NB_FUSED, 256, 0, stream>>>(rp, mB, mI, x1, invd, T2, T3, y2, y3, st2, st3);
    k_bnrelu <<<7500, 256, 0, stream>>>(y2, st2, g2, be2, x2);
    k_bnrelu <<<7500, 256, 0, stream>>>(y3, st3, g3, be3, x3);
    k_regr   <<<NB_FUSED, 256, 0, stream>>>(rp, mB, mI, x2, invd, Tr, br, out + REG_OFF);
    k_clsobj <<<NB_FUSED, 256, 0, stream>>>(rp, mB, mI, x3, invd, Tc, To, bc, bo, out, out + OBJ_OFF);
}

// Round 2
// 3169.974 us; speedup vs baseline: 1.0111x; 1.0111x over previous
//
#include <hip/hip_runtime.h>
#include <hip/hip_bf16.h>

// ---------------- problem constants ----------------
#define NN 30000
#define NE 480000
#define CIN 64
#define KD 1600          // 25*64 spline-K dimension
#define KT 1664          // + 64 root-append columns
#define KTILES 52        // 1664 / 32
#define KPA 1672         // padded A-tile row stride (elements)
#define NT 8             // nodes per fused block
#define NB_FUSED (NN/NT) // 3750
#define MC 256           // edge-metadata chunk staged in LDS
#define REG_OFF  (30000*101)
#define OBJ_OFF  (30000*105)

typedef short bf16x8 __attribute__((ext_vector_type(8)));
typedef float f32x4  __attribute__((ext_vector_type(4)));

__device__ __forceinline__ ushort f2bf(float x) {
    union { float f; unsigned u; } v; v.f = x;
    unsigned r = v.u + 0x7FFFu + ((v.u >> 16) & 1u);   // RNE
    return (ushort)(r >> 16);
}

// ---------------- graph preprocessing ----------------
__global__ void k_count(const int* __restrict__ dst, int* __restrict__ deg) {
    int e = blockIdx.x * 256 + threadIdx.x;
    if (e < NE) atomicAdd(&deg[dst[e]], 1);
}

__global__ void k_scan(const int* __restrict__ deg, int* __restrict__ rp,
                       int* __restrict__ cur, float* __restrict__ invd) {
    __shared__ int s[1024];
    int t = threadIdx.x;
    const int CH = 30;                       // 1024*30 >= 30000
    int base = t * CH, loc = 0;
    for (int i = 0; i < CH; ++i) { int n = base + i; if (n < NN) loc += deg[n]; }
    s[t] = loc; __syncthreads();
    for (int o = 1; o < 1024; o <<= 1) {
        int v = (t >= o) ? s[t - o] : 0;
        __syncthreads(); s[t] += v; __syncthreads();
    }
    int run = s[t] - loc;                    // exclusive prefix for this chunk
    for (int i = 0; i < CH; ++i) {
        int n = base + i;
        if (n < NN) {
            int dg = deg[n];
            rp[n] = run; cur[n] = run;
            invd[n] = 1.f / (float)(dg > 0 ? dg : 1);
            run += dg;
        }
    }
    if (t == 0) rp[NN] = NE;
}

// compute spline basis per edge and scatter metadata into dst-sorted order
__global__ void k_scatter(const float* __restrict__ ea, const int* __restrict__ src,
                          const int* __restrict__ dst, int* __restrict__ cur,
                          float4* __restrict__ mB, int4* __restrict__ mI) {
    int e = blockIdx.x * 256 + threadIdx.x;
    if (e >= NE) return;
    float p0 = ea[e*3+0], p1 = ea[e*3+1];
    float v0 = p0*4.f, v1 = p1*4.f;
    float b0 = fminf(fmaxf(floorf(v0),0.f),4.f);
    float b1 = fminf(fmaxf(floorf(v1),0.f),4.f);
    float f0 = v0-b0, f1 = v1-b1;
    int i0 = (int)b0, i1 = (int)b1;
    float Bv[4]; int kv[4];
    #pragma unroll
    for (int j = 0; j < 4; ++j) {
        int bit0 = j >> 1, bit1 = j & 1;
        int q0 = i0 + bit0; if (q0 > 4) q0 = 4;
        int q1 = i1 + bit1; if (q1 > 4) q1 = 4;
        float w0 = bit0 ? f0 : 1.f - f0;
        float w1 = bit1 ? f1 : 1.f - f1;
        Bv[j] = w0 * w1; kv[j] = q0*5 + q1;
    }
    unsigned kp = (unsigned)kv[0] | ((unsigned)kv[1]<<8) | ((unsigned)kv[2]<<16) | ((unsigned)kv[3]<<24);
    int dn = dst[e];
    int pos = atomicAdd(&cur[dn], 1);
    mB[pos] = make_float4(Bv[0],Bv[1],Bv[2],Bv[3]);
    mI[pos] = make_int4((int)kp, src[e], dn, 0);
}

// transpose+bf16 all 6 weight sets: Wt[d][kc] = W[kc][d] (kc<1600), = root[kc-1600][d]
__global__ void k_prepw(const float* W1,const float* R1,const float* W2,const float* R2,
                        const float* W3,const float* R3,const float* Wr,const float* Rr,
                        const float* Wc,const float* Rc,const float* Wo,const float* Ro,
                        ushort* T1, ushort* T2, ushort* T3, ushort* Tr, ushort* Tc, ushort* To) {
    int b = blockIdx.x;
    const float* W; const float* R; ushort* T; int od; int d;
    if      (b < 64)  { W=W1; R=R1; T=T1; od=64;  d=b;     }
    else if (b < 128) { W=W2; R=R2; T=T2; od=64;  d=b-64;  }
    else if (b < 192) { W=W3; R=R3; T=T3; od=64;  d=b-128; }
    else if (b < 208) { W=Wr; R=Rr; T=Tr; od=4;   d=b-192; }
    else if (b < 320) { W=Wc; R=Rc; T=Tc; od=101; d=b-208; }
    else              { W=Wo; R=Ro; T=To; od=1;   d=b-320; }
    for (int kc = threadIdx.x; kc < KT; kc += 256) {
        float v = 0.f;
        if (d < od) v = (kc < KD) ? W[(long)kc*od + d] : R[(long)(kc-KD)*od + d];
        T[(long)d*KT + kc] = f2bf(v);
    }
}

// ---------------- fused spline-conv building blocks ----------------
// 512 threads. LDS: accf[8*1600] f32 (reused as bf16 A-tile) + aux (meta / partials)
__device__ __forceinline__ void build_tile(int n0, const int* __restrict__ rp,
        const float4* __restrict__ mB, const int4* __restrict__ mI,
        const float* __restrict__ f, const float* __restrict__ invd,
        float* accf, ushort* accbh, float4* aux4) {
    const int tid = threadIdx.x;
    const int w = tid >> 6, l = tid & 63;
    float4* smB = aux4;                 // MC float4 = 4KB
    int2*  smI  = (int2*)(aux4 + MC);   // MC int2   = 2KB

    for (int q = tid; q < NT*KD/4; q += 512) ((float4*)accf)[q] = make_float4(0,0,0,0);
    __syncthreads();

    int beg = rp[n0], end = rp[n0 + NT];
    for (int cb = beg; cb < end; cb += MC) {
        int ce = cb + MC; if (ce > end) ce = end;
        int n = ce - cb;
        for (int t = tid; t < n; t += 512) {
            smB[t] = mB[cb + t];
            int4 v = mI[cb + t];
            smI[t] = make_int2(v.x, v.y | ((v.z - n0) << 20));
        }
        __syncthreads();
        // wave w handles edges t0 = w, w+8, ... in batches of 4
        for (int t0 = w; t0 < n; t0 += 32) {
            float4 b4[4]; int2 i2[4]; float xv[4];
            #pragma unroll
            for (int u = 0; u < 4; ++u) {
                int t = t0 + u*8;
                int ts = (t < n) ? t : 0;
                b4[u] = smB[ts]; i2[u] = smI[ts];
                if (t >= n) b4[u] = make_float4(0,0,0,0);
            }
            #pragma unroll
            for (int u = 0; u < 4; ++u) {
                int s = i2[u].y & 0xFFFFF;
                xv[u] = f[(long)s * CIN + l];
            }
            #pragma unroll
            for (int u = 0; u < 4; ++u) {
                int row = i2[u].y >> 20;
                float* base = accf + row*KD + l;
                int kp = i2[u].x;
                atomicAdd(base + ((kp      ) & 0xFF)*CIN, b4[u].x * xv[u]);
                atomicAdd(base + ((kp >>  8) & 0xFF)*CIN, b4[u].y * xv[u]);
                atomicAdd(base + ((kp >> 16) & 0xFF)*CIN, b4[u].z * xv[u]);
                atomicAdd(base + ((kp >> 24) & 0xFF)*CIN, b4[u].w * xv[u]);
            }
        }
        __syncthreads();
    }

    // stage to registers, then in-place f32 -> bf16 rewrite (with 1/deg)
    float4 st[7];
    #pragma unroll
    for (int u = 0; u < 7; ++u) {
        int q = tid + (u << 9);
        if (q < NT*KD/4) st[u] = ((const float4*)accf)[q];
    }
    float fa = f[(long)(n0 + w)*CIN + l];     // root-append value (8 rows x 64 ch = 512)
    __syncthreads();
    #pragma unroll
    for (int u = 0; u < 7; ++u) {
        int q = tid + (u << 9);
        if (q < NT*KD/4) {
            int row = q / 400;            // 400 float4 per row
            int c4  = (q % 400) * 4;
            float s = invd[n0 + row];
            ushort4 o;
            o.x = f2bf(st[u].x * s); o.y = f2bf(st[u].y * s);
            o.z = f2bf(st[u].z * s); o.w = f2bf(st[u].w * s);
            *(ushort4*)(accbh + row*KPA + c4) = o;
        }
    }
    accbh[w*KPA + KD + l] = f2bf(fa);
    __syncthreads();
}

// 16-col N-tile GEMM over kt in [k0, k0+NK): rows 0-7 valid (8-15 duplicate)
template<int NK>
__device__ __forceinline__ f32x4 sweepN(const ushort* accbh, const ushort* __restrict__ wt, int k0) {
    const int l = threadIdx.x & 63;
    const ushort* ap = accbh + (l & 7)*KPA + ((l >> 4) << 3) + k0*32;
    const ushort* bp = wt + (long)(l & 15)*KT + ((l >> 4) << 3) + k0*32;
    f32x4 d = {0.f,0.f,0.f,0.f};
    #pragma unroll
    for (int kt = 0; kt < NK; ++kt) {
        bf16x8 a = *(const bf16x8*)(ap + kt*32);
        bf16x8 b = *(const bf16x8*)(bp + kt*32);
        d = __builtin_amdgcn_mfma_f32_16x16x32_bf16(a, b, d, 0, 0, 0);
    }
    return d;
}

template<bool STATS, bool BIAS>
__device__ __forceinline__ void epilogue(f32x4 d, int n0, int colbase, int od, int ostride,
        const float* __restrict__ bias, float* __restrict__ out, float* __restrict__ stats) {
    const int l = threadIdx.x & 63;
    if (l >= 32) return;                      // lanes 32-63 hold duplicate rows
    int col = colbase + (l & 15);
    int rb = (l >> 4) << 2;                   // 0 or 4
    float bv = (BIAS && col < od) ? bias[col] : 0.f;
    float s1 = 0.f, s2 = 0.f;
    #pragma unroll
    for (int r = 0; r < 4; ++r) {
        float v = d[r] + bv;
        if (col < od) out[(long)(n0 + rb + r)*ostride + col] = v;
        s1 += v; s2 += v * v;
    }
    if (STATS) {
        s1 += __shfl_down(s1, 16);
        s2 += __shfl_down(s2, 16);
        if (l < 16) { atomicAdd(&stats[col], s1); atomicAdd(&stats[64 + col], s2); }
    }
}

// ---------------- fused conv kernels (512 threads) ----------------
__global__ __launch_bounds__(512,4) void k_conv1(const int* rp, const float4* mB, const int4* mI,
        const float* x, const float* invd, const ushort* T1, float* y1, float* st1) {
    __shared__ float accf[NT*KD];
    __shared__ float4 aux4[512];
    ushort* accbh = (ushort*)accf;
    int n0 = blockIdx.x * NT;
    build_tile(n0, rp, mB, mI, x, invd, accf, accbh, aux4);
    int tid = threadIdx.x, w = tid >> 6;
    int ct = w & 3, h = w >> 2;
    f32x4 d = sweepN<26>(accbh, T1 + (long)(ct << 4)*KT, h*26);
    f32x4* pb = (f32x4*)aux4;
    pb[tid] = d; __syncthreads();
    if (w < 4) {
        f32x4 o = pb[tid] + pb[tid + 256];
        epilogue<true,false>(o, n0, ct << 4, 64, 64, nullptr, y1, st1);
    }
}

__global__ __launch_bounds__(512,4) void k_conv23(const int* rp, const float4* mB, const int4* mI,
        const float* x1, const float* invd, const ushort* T2, const ushort* T3,
        float* y2, float* y3, float* st2, float* st3) {
    __shared__ float accf[NT*KD];
    __shared__ float4 aux4[512];
    ushort* accbh = (ushort*)accf;
    int n0 = blockIdx.x * NT;
    build_tile(n0, rp, mB, mI, x1, invd, accf, accbh, aux4);
    int tid = threadIdx.x, w = tid >> 6;
    int ct = w & 3, h = w >> 2;
    f32x4* pb = (f32x4*)aux4;
    f32x4 d2 = sweepN<26>(accbh, T2 + (long)(ct << 4)*KT, h*26);
    pb[tid] = d2; __syncthreads();
    if (w < 4) {
        f32x4 o = pb[tid] + pb[tid + 256];
        epilogue<true,false>(o, n0, ct << 4, 64, 64, nullptr, y2, st2);
    }
    __syncthreads();
    f32x4 d3 = sweepN<26>(accbh, T3 + (long)(ct << 4)*KT, h*26);
    pb[tid] = d3; __syncthreads();
    if (w < 4) {
        f32x4 o = pb[tid] + pb[tid + 256];
        epilogue<true,false>(o, n0, ct << 4, 64, 64, nullptr, y3, st3);
    }
}

__global__ __launch_bounds__(512,4) void k_regr(const int* rp, const float4* mB, const int4* mI,
        const float* x2, const float* invd, const ushort* Tr, const float* bias, float* outr) {
    __shared__ float accf[NT*KD];
    __shared__ float4 aux4[512];
    ushort* accbh = (ushort*)accf;
    int n0 = blockIdx.x * NT;
    build_tile(n0, rp, mB, mI, x2, invd, accf, accbh, aux4);
    int tid = threadIdx.x, w = tid >> 6, l = tid & 63;
    int kb = (w*52) >> 3, ke = ((w+1)*52) >> 3;
    const ushort* ap = accbh + (l & 7)*KPA + ((l >> 4) << 3);
    const ushort* bp = Tr + (long)(l & 15)*KT + ((l >> 4) << 3);
    f32x4 d = {0.f,0.f,0.f,0.f};
    for (int kt = kb; kt < ke; ++kt) {
        bf16x8 a = *(const bf16x8*)(ap + kt*32);
        bf16x8 b = *(const bf16x8*)(bp + kt*32);
        d = __builtin_amdgcn_mfma_f32_16x16x32_bf16(a, b, d, 0, 0, 0);
    }
    f32x4* pb = (f32x4*)aux4;
    pb[tid] = d; __syncthreads();
    if (w == 0) {
        f32x4 o = pb[l];
        #pragma unroll
        for (int i = 1; i < 8; ++i) o += pb[l + (i << 6)];
        epilogue<false,true>(o, n0, 0, 4, 4, bias, outr, nullptr);
    }
}

__global__ __launch_bounds__(512,4) void k_clsobj(const int* rp, const float4* mB, const int4* mI,
        const float* x3, const float* invd, const ushort* Tc, const ushort* To,
        const float* bc, const float* bo, float* outc, float* outo) {
    __shared__ float accf[NT*KD];
    __shared__ float4 aux4[512];
    ushort* accbh = (ushort*)accf;
    int n0 = blockIdx.x * NT;
    build_tile(n0, rp, mB, mI, x3, invd, accf, accbh, aux4);
    int w = threadIdx.x >> 6;
    const ushort* wt = (w < 7) ? (Tc + (long)(w << 4)*KT) : To;
    f32x4 d = sweepN<52>(accbh, wt, 0);
    if (w < 7) epilogue<false,true>(d, n0, w << 4, 101, 101, bc, outc, nullptr);
    else       epilogue<false,true>(d, n0, 0, 1, 1, bo, outo, nullptr);
}

// ---------------- BN + ReLU ----------------
__global__ void k_bnrelu(const float* __restrict__ y, const float* __restrict__ st,
                         const float* __restrict__ g, const float* __restrict__ bb,
                         float* __restrict__ xo) {
    int idx = blockIdx.x * 256 + threadIdx.x;
    if (idx >= NN*CIN) return;
    int d = idx & 63;
    const float inv_n = 1.f / (float)NN;
    float m = st[d] * inv_n;
    float var = st[64 + d] * inv_n - m * m;
    float v = (y[idx] - m) * rsqrtf(var + 1e-5f) * g[d] + bb[d];
    xo[idx] = fmaxf(v, 0.f);
}

// ---------------- host launch ----------------
extern "C" void kernel_launch(void* const* d_in, const int* in_sizes, int n_in,
                              void* d_out, int out_size, void* d_ws, size_t ws_size,
                              hipStream_t stream) {
    const float* x    = (const float*)d_in[0];
    const float* ea   = (const float*)d_in[1];
    const int*   src  = (const int*)d_in[2];
    const int*   dst  = (const int*)d_in[3];
    const float* W1   = (const float*)d_in[4];
    const float* R1   = (const float*)d_in[5];
    const float* g1   = (const float*)d_in[6];
    const float* be1  = (const float*)d_in[7];
    const float* W2   = (const float*)d_in[8];
    const float* R2   = (const float*)d_in[9];
    const float* g2   = (const float*)d_in[10];
    const float* be2  = (const float*)d_in[11];
    const float* W3   = (const float*)d_in[12];
    const float* R3   = (const float*)d_in[13];
    const float* g3   = (const float*)d_in[14];
    const float* be3  = (const float*)d_in[15];
    const float* Wr   = (const float*)d_in[16];
    const float* Rr   = (const float*)d_in[17];
    const float* br   = (const float*)d_in[18];
    const float* Wc   = (const float*)d_in[19];
    const float* Rc   = (const float*)d_in[20];
    const float* bc   = (const float*)d_in[21];
    const float* Wo   = (const float*)d_in[22];
    const float* Ro   = (const float*)d_in[23];
    const float* bo   = (const float*)d_in[24];
    float* out = (float*)d_out;

    char* p = (char*)d_ws;
    auto alloc = [&](size_t bytes) { char* r = p; p += (bytes + 255) & ~(size_t)255; return r; };
    float4* mB   = (float4*)alloc((size_t)NE * 16);
    int4*   mI   = (int4*)  alloc((size_t)NE * 16);
    int*    deg  = (int*)   alloc((size_t)NN * 4);
    int*    rp   = (int*)   alloc((size_t)(NN + 1) * 4);
    int*    cur  = (int*)   alloc((size_t)NN * 4);
    float*  invd = (float*) alloc((size_t)NN * 4);
    ushort* T1   = (ushort*)alloc((size_t)64  * KT * 2);
    ushort* T2   = (ushort*)alloc((size_t)64  * KT * 2);
    ushort* T3   = (ushort*)alloc((size_t)64  * KT * 2);
    ushort* Tr   = (ushort*)alloc((size_t)16  * KT * 2);
    ushort* Tc   = (ushort*)alloc((size_t)112 * KT * 2);
    ushort* To   = (ushort*)alloc((size_t)16  * KT * 2);
    float*  y1   = (float*) alloc((size_t)NN * CIN * 4);
    float*  y2   = (float*) alloc((size_t)NN * CIN * 4);
    float*  y3   = (float*) alloc((size_t)NN * CIN * 4);
    float*  x1   = (float*) alloc((size_t)NN * CIN * 4);
    float*  x2   = (float*) alloc((size_t)NN * CIN * 4);
    float*  x3   = (float*) alloc((size_t)NN * CIN * 4);
    float*  stats= (float*) alloc(3 * 128 * 4);
    float* st1 = stats, *st2 = stats + 128, *st3 = stats + 256;

    hipMemsetAsync(deg, 0, (size_t)NN * 4, stream);
    hipMemsetAsync(stats, 0, 3 * 128 * 4, stream);

    k_count  <<<1875, 256, 0, stream>>>(dst, deg);
    k_scan   <<<1, 1024, 0, stream>>>(deg, rp, cur, invd);
    k_scatter<<<1875, 256, 0, stream>>>(ea, src, dst, cur, mB, mI);
    k_prepw  <<<336, 256, 0, stream>>>(W1,R1,W2,R2,W3,R3,Wr,Rr,Wc,Rc,Wo,Ro,T1,T2,T3,Tr,Tc,To);

    k_conv1  <<<NB_FUSED, 512, 0, stream>>>(rp, mB, mI, x, invd, T1, y1, st1);
    k_bnrelu <<<7500, 256, 0, stream>>>(y1, st1, g1, be1, x1);
    k_conv23 <<<NB_FUSED, 512, 0, stream>>>(rp, mB, mI, x1, invd, T2, T3, y2, y3, st2, st3);
    k_bnrelu <<<7500, 256, 0, stream>>>(y2, st2, g2, be2, x2);
    k_bnrelu <<<7500, 256, 0, stream>>>(y3, st3, g3, be3, x3);
    k_regr   <<<NB_FUSED, 512, 0, stream>>>(rp, mB, mI, x2, invd, Tr, br, out + REG_OFF);
    k_clsobj <<<NB_FUSED, 512, 0, stream>>>(rp, mB, mI, x3, invd, Tc, To, bc, bo, out, out + OBJ_OFF);
}

// Round 3
// 873.008 us; speedup vs baseline: 3.6715x; 3.6311x over previous
//
#include <hip/hip_runtime.h>
#include <hip/hip_bf16.h>

// ---------------- problem constants ----------------
#define NN 30000
#define NE 480000
#define CIN 64
#define KD 1600          // 25*64 spline-K dimension
#define KT 1664          // + 64 root-append columns
#define KTILES 52        // 1664 / 32
#define KPA 1672         // padded A-tile row stride (elements)
#define NT 8             // nodes per fused block (= 8 waves, wave-per-node)
#define NB_FUSED (NN/NT) // 3750
#define REG_OFF  (30000*101)
#define OBJ_OFF  (30000*105)

typedef short bf16x8 __attribute__((ext_vector_type(8)));
typedef float f32x4  __attribute__((ext_vector_type(4)));

__device__ __forceinline__ ushort f2bf(float x) {
    union { float f; unsigned u; } v; v.f = x;
    unsigned r = v.u + 0x7FFFu + ((v.u >> 16) & 1u);   // RNE
    return (ushort)(r >> 16);
}

// ---------------- graph preprocessing ----------------
__global__ void k_count(const int* __restrict__ dst, int* __restrict__ deg) {
    int e = blockIdx.x * 256 + threadIdx.x;
    if (e < NE) atomicAdd(&deg[dst[e]], 1);
}

__global__ void k_scan(const int* __restrict__ deg, int* __restrict__ rp,
                       int* __restrict__ cur, float* __restrict__ invd) {
    __shared__ int s[1024];
    int t = threadIdx.x;
    const int CH = 30;                       // 1024*30 >= 30000
    int base = t * CH, loc = 0;
    for (int i = 0; i < CH; ++i) { int n = base + i; if (n < NN) loc += deg[n]; }
    s[t] = loc; __syncthreads();
    for (int o = 1; o < 1024; o <<= 1) {
        int v = (t >= o) ? s[t - o] : 0;
        __syncthreads(); s[t] += v; __syncthreads();
    }
    int run = s[t] - loc;                    // exclusive prefix for this chunk
    for (int i = 0; i < CH; ++i) {
        int n = base + i;
        if (n < NN) {
            int dg = deg[n];
            rp[n] = run; cur[n] = run;
            invd[n] = 1.f / (float)(dg > 0 ? dg : 1);
            run += dg;
        }
    }
    if (t == 0) rp[NN] = NE;
}

// compute spline basis per edge and scatter metadata into dst-sorted order
__global__ void k_scatter(const float* __restrict__ ea, const int* __restrict__ src,
                          const int* __restrict__ dst, int* __restrict__ cur,
                          float4* __restrict__ mB, int4* __restrict__ mI) {
    int e = blockIdx.x * 256 + threadIdx.x;
    if (e >= NE) return;
    float p0 = ea[e*3+0], p1 = ea[e*3+1];
    float v0 = p0*4.f, v1 = p1*4.f;
    float b0 = fminf(fmaxf(floorf(v0),0.f),4.f);
    float b1 = fminf(fmaxf(floorf(v1),0.f),4.f);
    float f0 = v0-b0, f1 = v1-b1;
    int i0 = (int)b0, i1 = (int)b1;
    float Bv[4]; int kv[4];
    #pragma unroll
    for (int j = 0; j < 4; ++j) {
        int bit0 = j >> 1, bit1 = j & 1;
        int q0 = i0 + bit0; if (q0 > 4) q0 = 4;
        int q1 = i1 + bit1; if (q1 > 4) q1 = 4;
        float w0 = bit0 ? f0 : 1.f - f0;
        float w1 = bit1 ? f1 : 1.f - f1;
        Bv[j] = w0 * w1; kv[j] = q0*5 + q1;
    }
    unsigned kp = (unsigned)kv[0] | ((unsigned)kv[1]<<8) | ((unsigned)kv[2]<<16) | ((unsigned)kv[3]<<24);
    int dn = dst[e];
    int pos = atomicAdd(&cur[dn], 1);
    mB[pos] = make_float4(Bv[0],Bv[1],Bv[2],Bv[3]);
    mI[pos] = make_int4((int)kp, src[e], dn, 0);
}

// transpose+bf16 all 6 weight sets: Wt[d][kc] = W[kc][d] (kc<1600), = root[kc-1600][d]
__global__ void k_prepw(const float* W1,const float* R1,const float* W2,const float* R2,
                        const float* W3,const float* R3,const float* Wr,const float* Rr,
                        const float* Wc,const float* Rc,const float* Wo,const float* Ro,
                        ushort* T1, ushort* T2, ushort* T3, ushort* Tr, ushort* Tc, ushort* To) {
    int b = blockIdx.x;
    const float* W; const float* R; ushort* T; int od; int d;
    if      (b < 64)  { W=W1; R=R1; T=T1; od=64;  d=b;     }
    else if (b < 128) { W=W2; R=R2; T=T2; od=64;  d=b-64;  }
    else if (b < 192) { W=W3; R=R3; T=T3; od=64;  d=b-128; }
    else if (b < 208) { W=Wr; R=Rr; T=Tr; od=4;   d=b-192; }
    else if (b < 320) { W=Wc; R=Rc; T=Tc; od=101; d=b-208; }
    else              { W=Wo; R=Ro; T=To; od=1;   d=b-320; }
    for (int kc = threadIdx.x; kc < KT; kc += 256) {
        float v = 0.f;
        if (d < od) v = (kc < KD) ? W[(long)kc*od + d] : R[(long)(kc-KD)*od + d];
        T[(long)d*KT + kc] = f2bf(v);
    }
}

// ---------------- fused spline-conv building blocks ----------------
// 512 threads. Wave w exclusively owns node n0+w: NO atomics, plain LDS RMW.
__device__ __forceinline__ void build_tile(int n0, const int* __restrict__ rp,
        const float4* __restrict__ mB, const int4* __restrict__ mI,
        const float* __restrict__ f, const float* __restrict__ invd,
        float* accf, ushort* accbh) {
    const int tid = threadIdx.x;
    const int w = tid >> 6, l = tid & 63;

    for (int q = tid; q < NT*KD/4; q += 512) ((float4*)accf)[q] = make_float4(0,0,0,0);
    __syncthreads();

    float* myrow = accf + w*KD + l;          // exclusive to this wave
    int beg = rp[n0 + w], end = rp[n0 + w + 1];
    for (int e0 = beg; e0 < end; e0 += 4) {
        int ne = end - e0;
        float4 b4[4]; int kp[4]; float xv[4];
        #pragma unroll
        for (int u = 0; u < 4; ++u) {
            int e = (u < ne) ? e0 + u : beg; // safe duplicate, contribution zeroed
            b4[u] = mB[e];
            int4 i4 = mI[e];
            kp[u] = i4.x;
            xv[u] = f[(long)i4.y * CIN + l];
            if (u >= ne) b4[u] = make_float4(0,0,0,0);
        }
        #pragma unroll
        for (int u = 0; u < 4; ++u) {
            int k0 = (kp[u]      ) & 0xFF;
            int k1 = (kp[u] >>  8) & 0xFF;
            int k2 = (kp[u] >> 16) & 0xFF;
            int k3 = (kp[u] >> 24) & 0xFF;
            // 4 corners of one edge are provably distinct k -> parallel RMW;
            // cross-edge aliasing is possible -> compiler keeps store->load order.
            float a0 = myrow[k0*CIN], a1 = myrow[k1*CIN];
            float a2 = myrow[k2*CIN], a3 = myrow[k3*CIN];
            myrow[k0*CIN] = a0 + b4[u].x * xv[u];
            myrow[k1*CIN] = a1 + b4[u].y * xv[u];
            myrow[k2*CIN] = a2 + b4[u].z * xv[u];
            myrow[k3*CIN] = a3 + b4[u].w * xv[u];
        }
    }
    __syncthreads();

    // stage to registers, then in-place f32 -> bf16 rewrite (with 1/deg)
    float4 st[7];
    #pragma unroll
    for (int u = 0; u < 7; ++u) {
        int q = tid + (u << 9);
        if (q < NT*KD/4) st[u] = ((const float4*)accf)[q];
    }
    float fa = f[(long)(n0 + w)*CIN + l];     // root-append value (8 rows x 64 ch = 512)
    __syncthreads();
    #pragma unroll
    for (int u = 0; u < 7; ++u) {
        int q = tid + (u << 9);
        if (q < NT*KD/4) {
            int row = q / 400;            // 400 float4 per row
            int c4  = (q % 400) * 4;
            float s = invd[n0 + row];
            ushort4 o;
            o.x = f2bf(st[u].x * s); o.y = f2bf(st[u].y * s);
            o.z = f2bf(st[u].z * s); o.w = f2bf(st[u].w * s);
            *(ushort4*)(accbh + row*KPA + c4) = o;
        }
    }
    accbh[w*KPA + KD + l] = f2bf(fa);
    __syncthreads();
}

// 16-col N-tile GEMM over kt in [k0, k0+NK): rows 0-7 valid (8-15 duplicate)
template<int NK>
__device__ __forceinline__ f32x4 sweepN(const ushort* accbh, const ushort* __restrict__ wt, int k0) {
    const int l = threadIdx.x & 63;
    const ushort* ap = accbh + (l & 7)*KPA + ((l >> 4) << 3) + k0*32;
    const ushort* bp = wt + (long)(l & 15)*KT + ((l >> 4) << 3) + k0*32;
    f32x4 d = {0.f,0.f,0.f,0.f};
    #pragma unroll
    for (int kt = 0; kt < NK; ++kt) {
        bf16x8 a = *(const bf16x8*)(ap + kt*32);
        bf16x8 b = *(const bf16x8*)(bp + kt*32);
        d = __builtin_amdgcn_mfma_f32_16x16x32_bf16(a, b, d, 0, 0, 0);
    }
    return d;
}

template<bool STATS, bool BIAS>
__device__ __forceinline__ void epilogue(f32x4 d, int n0, int colbase, int od, int ostride,
        const float* __restrict__ bias, float* __restrict__ out, float* __restrict__ stats) {
    const int l = threadIdx.x & 63;
    if (l >= 32) return;                      // lanes 32-63 hold duplicate rows
    int col = colbase + (l & 15);
    int rb = (l >> 4) << 2;                   // 0 or 4
    float bv = (BIAS && col < od) ? bias[col] : 0.f;
    float s1 = 0.f, s2 = 0.f;
    #pragma unroll
    for (int r = 0; r < 4; ++r) {
        float v = d[r] + bv;
        if (col < od) out[(long)(n0 + rb + r)*ostride + col] = v;
        s1 += v; s2 += v * v;
    }
    if (STATS) {
        s1 += __shfl_down(s1, 16);
        s2 += __shfl_down(s2, 16);
        if (l < 16) { atomicAdd(&stats[col], s1); atomicAdd(&stats[64 + col], s2); }
    }
}

// ---------------- fused conv kernels (512 threads) ----------------
__global__ __launch_bounds__(512,4) void k_conv1(const int* rp, const float4* mB, const int4* mI,
        const float* x, const float* invd, const ushort* T1, float* y1, float* st1) {
    __shared__ float accf[NT*KD];
    __shared__ float4 aux4[512];
    ushort* accbh = (ushort*)accf;
    int n0 = blockIdx.x * NT;
    build_tile(n0, rp, mB, mI, x, invd, accf, accbh);
    int tid = threadIdx.x, w = tid >> 6;
    int ct = w & 3, h = w >> 2;
    f32x4 d = sweepN<26>(accbh, T1 + (long)(ct << 4)*KT, h*26);
    f32x4* pb = (f32x4*)aux4;
    pb[tid] = d; __syncthreads();
    if (w < 4) {
        f32x4 o = pb[tid] + pb[tid + 256];
        epilogue<true,false>(o, n0, ct << 4, 64, 64, nullptr, y1, st1);
    }
}

__global__ __launch_bounds__(512,4) void k_conv23(const int* rp, const float4* mB, const int4* mI,
        const float* x1, const float* invd, const ushort* T2, const ushort* T3,
        float* y2, float* y3, float* st2, float* st3) {
    __shared__ float accf[NT*KD];
    __shared__ float4 aux4[512];
    ushort* accbh = (ushort*)accf;
    int n0 = blockIdx.x * NT;
    build_tile(n0, rp, mB, mI, x1, invd, accf, accbh);
    int tid = threadIdx.x, w = tid >> 6;
    int ct = w & 3, h = w >> 2;
    f32x4* pb = (f32x4*)aux4;
    f32x4 d2 = sweepN<26>(accbh, T2 + (long)(ct << 4)*KT, h*26);
    pb[tid] = d2; __syncthreads();
    if (w < 4) {
        f32x4 o = pb[tid] + pb[tid + 256];
        epilogue<true,false>(o, n0, ct << 4, 64, 64, nullptr, y2, st2);
    }
    __syncthreads();
    f32x4 d3 = sweepN<26>(accbh, T3 + (long)(ct << 4)*KT, h*26);
    pb[tid] = d3; __syncthreads();
    if (w < 4) {
        f32x4 o = pb[tid] + pb[tid + 256];
        epilogue<true,false>(o, n0, ct << 4, 64, 64, nullptr, y3, st3);
    }
}

__global__ __launch_bounds__(512,4) void k_regr(const int* rp, const float4* mB, const int4* mI,
        const float* x2, const float* invd, const ushort* Tr, const float* bias, float* outr) {
    __shared__ float accf[NT*KD];
    __shared__ float4 aux4[512];
    ushort* accbh = (ushort*)accf;
    int n0 = blockIdx.x * NT;
    build_tile(n0, rp, mB, mI, x2, invd, accf, accbh);
    int tid = threadIdx.x, w = tid >> 6, l = tid & 63;
    int kb = (w*52) >> 3, ke = ((w+1)*52) >> 3;
    const ushort* ap = accbh + (l & 7)*KPA + ((l >> 4) << 3);
    const ushort* bp = Tr + (long)(l & 15)*KT + ((l >> 4) << 3);
    f32x4 d = {0.f,0.f,0.f,0.f};
    for (int kt = kb; kt < ke; ++kt) {
        bf16x8 a = *(const bf16x8*)(ap + kt*32);
        bf16x8 b = *(const bf16x8*)(bp + kt*32);
        d = __builtin_amdgcn_mfma_f32_16x16x32_bf16(a, b, d, 0, 0, 0);
    }
    f32x4* pb = (f32x4*)aux4;
    pb[tid] = d; __syncthreads();
    if (w == 0) {
        f32x4 o = pb[l];
        #pragma unroll
        for (int i = 1; i < 8; ++i) o += pb[l + (i << 6)];
        epilogue<false,true>(o, n0, 0, 4, 4, bias, outr, nullptr);
    }
}

__global__ __launch_bounds__(512,4) void k_clsobj(const int* rp, const float4* mB, const int4* mI,
        const float* x3, const float* invd, const ushort* Tc, const ushort* To,
        const float* bc, const float* bo, float* outc, float* outo) {
    __shared__ float accf[NT*KD];
    ushort* accbh = (ushort*)accf;
    int n0 = blockIdx.x * NT;
    build_tile(n0, rp, mB, mI, x3, invd, accf, accbh);
    int w = threadIdx.x >> 6;
    const ushort* wt = (w < 7) ? (Tc + (long)(w << 4)*KT) : To;
    f32x4 d = sweepN<52>(accbh, wt, 0);
    if (w < 7) epilogue<false,true>(d, n0, w << 4, 101, 101, bc, outc, nullptr);
    else       epilogue<false,true>(d, n0, 0, 1, 1, bo, outo, nullptr);
}

// ---------------- BN + ReLU ----------------
__global__ void k_bnrelu(const float* __restrict__ y, const float* __restrict__ st,
                         const float* __restrict__ g, const float* __restrict__ bb,
                         float* __restrict__ xo) {
    int idx = blockIdx.x * 256 + threadIdx.x;
    if (idx >= NN*CIN) return;
    int d = idx & 63;
    const float inv_n = 1.f / (float)NN;
    float m = st[d] * inv_n;
    float var = st[64 + d] * inv_n - m * m;
    float v = (y[idx] - m) * rsqrtf(var + 1e-5f) * g[d] + bb[d];
    xo[idx] = fmaxf(v, 0.f);
}

// ---------------- host launch ----------------
extern "C" void kernel_launch(void* const* d_in, const int* in_sizes, int n_in,
                              void* d_out, int out_size, void* d_ws, size_t ws_size,
                              hipStream_t stream) {
    const float* x    = (const float*)d_in[0];
    const float* ea   = (const float*)d_in[1];
    const int*   src  = (const int*)d_in[2];
    const int*   dst  = (const int*)d_in[3];
    const float* W1   = (const float*)d_in[4];
    const float* R1   = (const float*)d_in[5];
    const float* g1   = (const float*)d_in[6];
    const float* be1  = (const float*)d_in[7];
    const float* W2   = (const float*)d_in[8];
    const float* R2   = (const float*)d_in[9];
    const float* g2   = (const float*)d_in[10];
    const float* be2  = (const float*)d_in[11];
    const float* W3   = (const float*)d_in[12];
    const float* R3   = (const float*)d_in[13];
    const float* g3   = (const float*)d_in[14];
    const float* be3  = (const float*)d_in[15];
    const float* Wr   = (const float*)d_in[16];
    const float* Rr   = (const float*)d_in[17];
    const float* br   = (const float*)d_in[18];
    const float* Wc   = (const float*)d_in[19];
    const float* Rc   = (const float*)d_in[20];
    const float* bc   = (const float*)d_in[21];
    const float* Wo   = (const float*)d_in[22];
    const float* Ro   = (const float*)d_in[23];
    const float* bo   = (const float*)d_in[24];
    float* out = (float*)d_out;

    char* p = (char*)d_ws;
    auto alloc = [&](size_t bytes) { char* r = p; p += (bytes + 255) & ~(size_t)255; return r; };
    float4* mB   = (float4*)alloc((size_t)NE * 16);
    int4*   mI   = (int4*)  alloc((size_t)NE * 16);
    int*    deg  = (int*)   alloc((size_t)NN * 4);
    int*    rp   = (int*)   alloc((size_t)(NN + 1) * 4);
    int*    cur  = (int*)   alloc((size_t)NN * 4);
    float*  invd = (float*) alloc((size_t)NN * 4);
    ushort* T1   = (ushort*)alloc((size_t)64  * KT * 2);
    ushort* T2   = (ushort*)alloc((size_t)64  * KT * 2);
    ushort* T3   = (ushort*)alloc((size_t)64  * KT * 2);
    ushort* Tr   = (ushort*)alloc((size_t)16  * KT * 2);
    ushort* Tc   = (ushort*)alloc((size_t)112 * KT * 2);
    ushort* To   = (ushort*)alloc((size_t)16  * KT * 2);
    float*  y1   = (float*) alloc((size_t)NN * CIN * 4);
    float*  y2   = (float*) alloc((size_t)NN * CIN * 4);
    float*  y3   = (float*) alloc((size_t)NN * CIN * 4);
    float*  x1   = (float*) alloc((size_t)NN * CIN * 4);
    float*  x2   = (float*) alloc((size_t)NN * CIN * 4);
    float*  x3   = (float*) alloc((size_t)NN * CIN * 4);
    float*  stats= (float*) alloc(3 * 128 * 4);
    float* st1 = stats, *st2 = stats + 128, *st3 = stats + 256;

    hipMemsetAsync(deg, 0, (size_t)NN * 4, stream);
    hipMemsetAsync(stats, 0, 3 * 128 * 4, stream);

    k_count  <<<1875, 256, 0, stream>>>(dst, deg);
    k_scan   <<<1, 1024, 0, stream>>>(deg, rp, cur, invd);
    k_scatter<<<1875, 256, 0, stream>>>(ea, src, dst, cur, mB, mI);
    k_prepw  <<<336, 256, 0, stream>>>(W1,R1,W2,R2,W3,R3,Wr,Rr,Wc,Rc,Wo,Ro,T1,T2,T3,Tr,Tc,To);

    k_conv1  <<<NB_FUSED, 512, 0, stream>>>(rp, mB, mI, x, invd, T1, y1, st1);
    k_bnrelu <<<7500, 256, 0, stream>>>(y1, st1, g1, be1, x1);
    k_conv23 <<<NB_FUSED, 512, 0, stream>>>(rp, mB, mI, x1, invd, T2, T3, y2, y3, st2, st3);
    k_bnrelu <<<7500, 256, 0, stream>>>(y2, st2, g2, be2, x2);
    k_bnrelu <<<7500, 256, 0, stream>>>(y3, st3, g3, be3, x3);
    k_regr   <<<NB_FUSED, 512, 0, stream>>>(rp, mB, mI, x2, invd, Tr, br, out + REG_OFF);
    k_clsobj <<<NB_FUSED, 512, 0, stream>>>(rp, mB, mI, x3, invd, Tc, To, bc, bo, out, out + OBJ_OFF);
}